// Round 12
// baseline (291.274 us; speedup 1.0000x reference)
//
#include <hip/hip_runtime.h>
#include <hip/hip_bf16.h>

typedef __attribute__((ext_vector_type(8))) short bf16x8;
typedef __attribute__((ext_vector_type(4))) short bf16x4;
typedef __attribute__((ext_vector_type(4))) float f32x4;
typedef __attribute__((ext_vector_type(16))) float f32x16;
typedef __attribute__((ext_vector_type(4))) unsigned u32x4;

__device__ inline short f2bf(float f) {
    unsigned u = __builtin_bit_cast(unsigned, f);
    u += 0x7FFF + ((u >> 16) & 1);   // round-to-nearest-even
    return (short)(u >> 16);
}

// ws layout (units: shorts/bf16):
//   0        : Q   [32][2048][64]
//   4194304  : K   [32][2048][64]
//   8388608  : V^T [32][64][2048]
//   12582912 : xq_bf16 [4096][1024]
//   16777216 : xk_bf16 [4096][1024]
//   20971520 : Wq_bf16 [1024][1024]; +1M: Wk; +2M: Wv
//   24117248 : mask bias f32[2][2048] (= 0 or -1e9), 16KB

// ---------------------------------------------------------------------------
// f32 -> bf16 convert (memory-bound) + mask-bias build (block 11264).
// ---------------------------------------------------------------------------
__global__ __launch_bounds__(256) void cvt_bf16(
    const float* __restrict__ xq, const float* __restrict__ xk,
    const float* __restrict__ Wq, const float* __restrict__ Wk,
    const float* __restrict__ Wv, const int* __restrict__ key_mask,
    short* __restrict__ ws)
{
    const int blk = blockIdx.x;
    if (blk >= 11264) {
        float* bias = (float*)(ws + 24117248u);
        const int i0 = threadIdx.x * 4;
#pragma unroll
        for (int p = 0; p < 4; ++p) {
            int idx = p * 1024 + i0;          // 0..4095 = mb*2048 + k
            int4 m = *(const int4*)&key_mask[idx];
            f32x4 o = { m.x ? 0.f : -1e9f, m.y ? 0.f : -1e9f,
                        m.z ? 0.f : -1e9f, m.w ? 0.f : -1e9f };
            *(f32x4*)&bias[idx] = o;
        }
        return;
    }
    int seg, local;
    if (blk < 4096)      { seg = 0; local = blk; }
    else if (blk < 8192) { seg = 1; local = blk - 4096; }
    else                 { seg = 2 + ((blk - 8192) >> 10); local = (blk - 8192) & 1023; }
    const float* src = (seg == 0) ? xq : (seg == 1) ? xk
                     : (seg == 2) ? Wq : (seg == 3) ? Wk : Wv;
    const size_t dstoff = (seg == 0) ? 12582912u : (seg == 1) ? 16777216u
                        : 20971520u + (size_t)(seg - 2) * 1048576u;
    const size_t idx = (size_t)local * 1024 + threadIdx.x * 4;
    float4 v = *(const float4*)&src[idx];
    bf16x4 o = { f2bf(v.x), f2bf(v.y), f2bf(v.z), f2bf(v.w) };
    *(bf16x4*)&ws[dstoff + idx] = o;
}

// ---------------------------------------------------------------------------
// Projection GEMM (bf16): out = x @ W^T + bias.
// z=0: Q -> [bh][t][64]   z=1: K -> [bh][t][64]   z=2: V -> [bh][64][t]
// T2 swizzle both-sides (R9-verified). R12: __launch_bounds__(256,4) caps
// VGPR at 128 (was 132 — 4 over the occupancy cliff) -> 3 blocks/CU resident.
// ---------------------------------------------------------------------------
__global__ __launch_bounds__(256, 4) void proj_gemm(
    short* __restrict__ ws, const float* __restrict__ bq,
    const float* __restrict__ bk, const float* __restrict__ bv)
{
    const int z = blockIdx.z;
    const short* A  = ws + ((z == 0) ? 12582912u : 16777216u);
    const short* Bw = ws + 20971520u + (size_t)z * 1048576u;
    const float* bias = (z == 0) ? bq : (z == 1) ? bk : bv;
    short* out = ws + (size_t)z * 4194304u;

    const int m0 = blockIdx.x * 128;
    const int n0 = blockIdx.y * 128;
    const int tid  = threadIdx.x;
    const int lane = tid & 63;
    const int wid  = tid >> 6;
    const int wr = wid >> 1, wc = wid & 1;
    const int l15 = lane & 15, lhi = lane >> 4;

    __shared__ alignas(16) short SM[17408];

    const int srow = wid * 32 + (lane >> 2);
    const int sgrp = (lane & 3) ^ ((lane >> 3) & 3);
    const short* aSrc = A  + (size_t)(m0 + srow) * 1024 + sgrp * 8;
    const short* bSrc = Bw + (size_t)(n0 + srow) * 1024 + sgrp * 8;

#define PSTAGE(T, BUF) do {                                                    \
    _Pragma("unroll")                                                          \
    for (int i_ = 0; i_ < 2; ++i_) {                                           \
        __builtin_amdgcn_global_load_lds(                                      \
            (const __attribute__((address_space(1))) unsigned*)                \
                (aSrc + (T) * 32 + i_ * 16384),                                \
            (__attribute__((address_space(3))) unsigned*)                      \
                &SM[(BUF) * 8192 + (wid * 32 + i_ * 16) * 32], 16, 0, 0);      \
        __builtin_amdgcn_global_load_lds(                                      \
            (const __attribute__((address_space(1))) unsigned*)                \
                (bSrc + (T) * 32 + i_ * 16384),                                \
            (__attribute__((address_space(3))) unsigned*)                      \
                &SM[(BUF) * 8192 + 4096 + (wid * 32 + i_ * 16) * 32], 16, 0, 0);\
    } } while (0)

    f32x4 acc[4][4] = {};

    const int rgrp = (lhi ^ ((l15 >> 1) & 3)) * 8;

    PSTAGE(0, 0);
    for (int t = 0; t < 32; ++t) {
        const int buf = t & 1;
        __syncthreads();
        if (t < 31) PSTAGE(t + 1, buf ^ 1);

        const short* SA = &SM[buf * 8192];
        const short* SB = SA + 4096;
        bf16x8 a[4], b[4];
#pragma unroll
        for (int i = 0; i < 4; ++i)
            a[i] = *(const bf16x8*)&SA[(wr * 64 + i * 16 + l15) * 32 + rgrp];
#pragma unroll
        for (int j = 0; j < 4; ++j)
            b[j] = *(const bf16x8*)&SB[(wc * 64 + j * 16 + l15) * 32 + rgrp];

        if (z == 2) {
#pragma unroll
            for (int i = 0; i < 4; ++i)
#pragma unroll
                for (int j = 0; j < 4; ++j)
                    acc[i][j] = __builtin_amdgcn_mfma_f32_16x16x32_bf16(
                        a[i], b[j], acc[i][j], 0, 0, 0);
        } else {
#pragma unroll
            for (int i = 0; i < 4; ++i)
#pragma unroll
                for (int j = 0; j < 4; ++j)
                    acc[i][j] = __builtin_amdgcn_mfma_f32_16x16x32_bf16(
                        b[j], a[i], acc[i][j], 0, 0, 0);
        }
    }
#undef PSTAGE

    __syncthreads();
    if (z == 2) {
#pragma unroll
        for (int i = 0; i < 4; ++i) {
            int mm = wr * 64 + i * 16 + lhi * 4;
#pragma unroll
            for (int j = 0; j < 4; ++j) {
                int nn = wc * 64 + j * 16 + l15;
                float bval = bias[n0 + nn];
                bf16x4 pk = { f2bf(acc[i][j][0] + bval), f2bf(acc[i][j][1] + bval),
                              f2bf(acc[i][j][2] + bval), f2bf(acc[i][j][3] + bval) };
                *(bf16x4*)&SM[nn * 136 + mm] = pk;
            }
        }
    } else {
#pragma unroll
        for (int i = 0; i < 4; ++i) {
            int mm = wr * 64 + i * 16 + l15;
#pragma unroll
            for (int j = 0; j < 4; ++j) {
                int nnb = wc * 64 + j * 16 + lhi * 4;
                float4 bw = *(const float4*)&bias[n0 + nnb];
                bf16x4 pk = { f2bf(acc[i][j][0] + bw.x), f2bf(acc[i][j][1] + bw.y),
                              f2bf(acc[i][j][2] + bw.z), f2bf(acc[i][j][3] + bw.w) };
                *(bf16x4*)&SM[mm * 136 + nnb] = pk;
            }
        }
    }
    __syncthreads();

    const int bb = m0 >> 11;
    const int mt = m0 & 2047;
#pragma unroll
    for (int p = 0; p < 8; ++p) {
        int id = p * 256 + tid;
        int rr = id >> 4;
        int g  = id & 15;
        bf16x8 v = *(const bf16x8*)&SM[rr * 136 + g * 8];
        if (z == 2) {
            int nn = n0 + rr, h = nn >> 6, d = nn & 63;
            *(bf16x8*)&out[(((size_t)(bb * 16 + h)) * 64 + d) * 2048 + mt + g * 8] = v;
        } else {
            int nn = n0 + g * 8, h = nn >> 6, d = nn & 63;
            *(bf16x8*)&out[(((size_t)(bb * 16 + h)) * 2048 + mt + rr) * 64 + d] = v;
        }
    }
}

// ---------------------------------------------------------------------------
// Flash attention, in-block split-K (unchanged, R11-verified): fixed-offset
// softmax, per-s register-safe processing, lv4 sum accumulator, mask-as-C-init,
// swizzled staging, setprio, pure-add split-K merge.
// ---------------------------------------------------------------------------
__device__ inline float pair_sum(float v) { return v + __shfl_xor(v, 32); }

__global__ __launch_bounds__(512, 4) void attn_fwd(
    const short* __restrict__ Qb, const short* __restrict__ Kb,
    const short* __restrict__ Vtb, const int* __restrict__ key_mask,
    const float* __restrict__ biasArr, float* __restrict__ out)
{
    const int bh = blockIdx.x;        // bh fastest: same-bh blocks -> same XCD
    const int qb = blockIdx.y;
    const int b  = bh >> 4;
    const int h  = bh & 15;
    const int mb = bh & 1;            // (b*H + h) % B, B=2
    const int tid  = threadIdx.x;
    const int lane = tid & 63;
    const int wid  = tid >> 6;        // 0..7
    const int qg   = wid & 3;         // q-group
    const int ks   = wid >> 2;        // k-split half
    const int l31  = lane & 31;
    const int hi   = lane >> 5;

    const size_t base = (size_t)bh * 2048 * 64;
    const int q0 = qb * 128 + qg * 32;
    const int ko = ks * 1024;

    __shared__ alignas(16) char SMEM[65536];
    short* KVbase = (short*)SMEM + ks * 16384;
#define KVS(BUF) (KVbase + (BUF) * 8192)

    const int* km_row = key_mask + mb * 2048;
    const float* bias_row = biasArr + mb * 2048;

    bf16x8 qf[4];
#pragma unroll
    for (int kf = 0; kf < 4; ++kf)
        qf[kf] = *(const bf16x8*)&Qb[base + (size_t)(q0 + l31) * 64 + kf * 16 + hi * 8];

    const int lrow = lane >> 3;
    const int lcol = (lane & 7) ^ (lrow & 7);
    const short* srcK[2];
    const short* srcV[2];
#pragma unroll
    for (int i = 0; i < 2; ++i) {
        int r0 = qg * 16 + i * 8;
        srcK[i] = Kb  + base + (size_t)(ko + r0 + lrow) * 64 + lcol * 8;
        srcV[i] = Vtb + base + (size_t)(r0 + lrow) * 2048 + ko + lcol * 8;
    }

    f32x16 acc[2];
#pragma unroll
    for (int n = 0; n < 2; ++n)
#pragma unroll
        for (int r = 0; r < 16; ++r) acc[n][r] = 0.f;
    float lv4_0 = 0.f, lv4_1 = 0.f, lv4_2 = 0.f, lv4_3 = 0.f;
    const float SC  = 0.18033688f;    // 0.125 * log2(e)
    const float MSC = 8.0f;           // fixed softmax offset (exp2 units)

#define STAGE(T, BUF)                                                          \
    {                                                                          \
        _Pragma("unroll")                                                      \
        for (int i = 0; i < 2; ++i) {                                          \
            int r0 = qg * 16 + i * 8;                                          \
            __builtin_amdgcn_global_load_lds(                                  \
                (const __attribute__((address_space(1))) unsigned int*)        \
                    (srcK[i] + (size_t)(T) * 4096),                            \
                (__attribute__((address_space(3))) unsigned int*)              \
                    &KVS(BUF)[r0 * 64],                                        \
                16, 0, 0);                                                     \
            __builtin_amdgcn_global_load_lds(                                  \
                (const __attribute__((address_space(1))) unsigned int*)        \
                    (srcV[i] + (size_t)(T) * 64),                              \
                (__attribute__((address_space(3))) unsigned int*)              \
                    &KVS(BUF)[4096 + r0 * 64],                                 \
                16, 0, 0);                                                     \
        }                                                                      \
    }

    STAGE(0, 0);

    for (int t = 0; t < 16; ++t) {
        const int buf = t & 1;
        const int k0 = ko + t * 64;
        __syncthreads();
        if (t < 15) STAGE(t + 1, buf ^ 1);

        // S^T = K*Q^T with C initialized to the mask bias (0 / -1e9).
        const f32x4* bp = (const f32x4*)(bias_row + k0);
        f32x16 sacc[2];
#pragma unroll
        for (int s = 0; s < 2; ++s) {
#pragma unroll
            for (int g = 0; g < 4; ++g) {
                f32x4 bv = bp[s * 8 + g * 2 + hi];
#pragma unroll
                for (int c = 0; c < 4; ++c) sacc[s][g * 4 + c] = bv[c];
            }
        }
        __builtin_amdgcn_s_setprio(1);
#pragma unroll
        for (int s = 0; s < 2; ++s) {
#pragma unroll
            for (int kf = 0; kf < 4; ++kf) {
                int row = s * 32 + l31;
                int xg = ((2 * kf + hi) ^ (row & 7)) * 8;
                bf16x8 kfr = *(const bf16x8*)&KVS(buf)[row * 64 + xg];
                sacc[s] = __builtin_amdgcn_mfma_f32_32x32x16_bf16(
                    kfr, qf[kf], sacc[s], 0, 0, 0);
            }
        }
        __builtin_amdgcn_s_setprio(0);

        // fixed-offset softmax, per-s to bound register pressure
        unsigned pk2[2][4][2];
#pragma unroll
        for (int s = 0; s < 2; ++s) {
            float p[16];
#pragma unroll
            for (int r = 0; r < 16; ++r)
                p[r] = __builtin_amdgcn_exp2f(sacc[s][r] * SC - MSC);
            lv4_0 += (p[0] + p[4]) + (p[8]  + p[12]);
            lv4_1 += (p[1] + p[5]) + (p[9]  + p[13]);
            lv4_2 += (p[2] + p[6]) + (p[10] + p[14]);
            lv4_3 += (p[3] + p[7]) + (p[11] + p[15]);
#pragma unroll
            for (int g = 0; g < 4; ++g)
#pragma unroll
                for (int w = 0; w < 2; ++w) {
                    unsigned d;
                    asm("v_cvt_pk_bf16_f32 %0, %1, %2"
                        : "=v"(d)
                        : "v"(p[g * 4 + 2 * w]), "v"(p[g * 4 + 2 * w + 1]));
                    pk2[s][g][w] = d;
                }
        }

        __builtin_amdgcn_s_setprio(1);
#pragma unroll
        for (int s = 0; s < 2; ++s)
#pragma unroll
            for (int kk = 0; kk < 2; ++kk) {
                unsigned w0 = pk2[s][2 * kk][0],     w1 = pk2[s][2 * kk][1];
                unsigned w2 = pk2[s][2 * kk + 1][0], w3 = pk2[s][2 * kk + 1][1];
                asm("v_permlane32_swap_b32 %0, %1" : "+v"(w0), "+v"(w2));
                asm("v_permlane32_swap_b32 %0, %1" : "+v"(w1), "+v"(w3));
                u32x4 fv = { w0, w1, w2, w3 };
                bf16x8 pf = __builtin_bit_cast(bf16x8, fv);
                int kq = s * 2 + kk;
#pragma unroll
                for (int n = 0; n < 2; ++n) {
                    int row = n * 32 + l31;
                    int xg = ((2 * kq + hi) ^ (row & 7)) * 8;
                    bf16x8 vf = *(const bf16x8*)&KVS(buf)[4096 + row * 64 + xg];
                    acc[n] = __builtin_amdgcn_mfma_f32_32x32x16_bf16(
                        vf, pf, acc[n], 0, 0, 0);
                }
            }
        __builtin_amdgcn_s_setprio(0);
    }
#undef STAGE
#undef KVS

    // final row-sum (once) + cross-half
    float lr = pair_sum((lv4_0 + lv4_1) + (lv4_2 + lv4_3));

    // ---- split-K merge (pure add: same fixed offset both halves) ----
    __syncthreads();                       // (A) all KV reads complete
    float* R = (float*)SMEM + qg * 2176;   // per-qg region: O[64][32] | l

    if (ks == 1) {
#pragma unroll
        for (int n = 0; n < 2; ++n)
#pragma unroll
            for (int r = 0; r < 16; ++r) {
                int d = n * 32 + (r & 3) + 8 * (r >> 2) + 4 * hi;
                R[d * 32 + l31] = acc[n][r];
            }
        if (hi == 0) R[2048 + l31] = lr;
    }
    __syncthreads();                       // (B) partner data visible

    if (ks == 0) {
        float l1 = R[2048 + l31];
        float o1[2][16];
#pragma unroll
        for (int n = 0; n < 2; ++n)
#pragma unroll
            for (int r = 0; r < 16; ++r) {
                int d = n * 32 + (r & 3) + 8 * (r >> 2) + 4 * hi;
                o1[n][r] = R[d * 32 + l31];
            }
        float qn = (float)km_row[q0 + l31] / (lr + l1);

#pragma unroll
        for (int n = 0; n < 2; ++n)
#pragma unroll
            for (int r = 0; r < 16; ++r) {
                int d = n * 32 + (r & 3) + 8 * (r >> 2) + 4 * hi;
                R[l31 * 68 + d] = (acc[n][r] + o1[n][r]) * qn;
            }
        const int l15 = lane & 15, lq = lane >> 4;
#pragma unroll
        for (int rep = 0; rep < 8; ++rep) {
            int qr = rep * 4 + lq;
            f32x4 v = *(const f32x4*)&R[qr * 68 + l15 * 4];
            *(f32x4*)&out[((size_t)b * 2048 + q0 + qr) * 1024 + h * 64 + l15 * 4] = v;
        }
    }
}

extern "C" void kernel_launch(void* const* d_in, const int* in_sizes, int n_in,
                              void* d_out, int out_size, void* d_ws, size_t ws_size,
                              hipStream_t stream) {
    const float* queries = (const float*)d_in[0];
    const float* keys    = (const float*)d_in[1];
    const int*   key_mask= (const int*)d_in[2];
    const float* Wq = (const float*)d_in[3];
    const float* bq = (const float*)d_in[4];
    const float* Wk = (const float*)d_in[5];
    const float* bk = (const float*)d_in[6];
    const float* Wv = (const float*)d_in[7];
    const float* bv = (const float*)d_in[8];
    float* out = (float*)d_out;

    short* ws = (short*)d_ws;
    const float* biasArr = (const float*)(ws + 24117248u);

    cvt_bf16<<<11265, 256, 0, stream>>>(queries, keys, Wq, Wk, Wv, key_mask, ws);

    proj_gemm<<<dim3(32, 8, 3), 256, 0, stream>>>(ws, bq, bk, bv);

    attn_fwd<<<dim3(32, 16), 512, 0, stream>>>(
        ws, ws + 4194304, ws + 2 * 4194304, key_mask, biasArr, out);
}

// Round 13
// 113.158 us; speedup vs baseline: 2.5740x; 2.5740x over previous
//
#include <hip/hip_runtime.h>
#include <hip/hip_bf16.h>

typedef __attribute__((ext_vector_type(8))) short bf16x8;
typedef __attribute__((ext_vector_type(4))) short bf16x4;
typedef __attribute__((ext_vector_type(4))) float f32x4;
typedef __attribute__((ext_vector_type(16))) float f32x16;
typedef __attribute__((ext_vector_type(4))) unsigned u32x4;

__device__ inline short f2bf(float f) {
    unsigned u = __builtin_bit_cast(unsigned, f);
    u += 0x7FFF + ((u >> 16) & 1);   // round-to-nearest-even
    return (short)(u >> 16);
}

// ws layout (units: shorts/bf16):
//   0        : Q   [32][2048][64]
//   4194304  : K   [32][2048][64]
//   8388608  : V^T [32][64][2048]
//   12582912 : xq_bf16 [4096][1024]
//   16777216 : xk_bf16 [4096][1024]
//   20971520 : Wq_bf16 [1024][1024]; +1M: Wk; +2M: Wv
//   24117248 : mask bias f32[2][2048] (= 0 or -1e9), 16KB

// ---------------------------------------------------------------------------
// f32 -> bf16 convert (memory-bound) + mask-bias build (block 11264).
// ---------------------------------------------------------------------------
__global__ __launch_bounds__(256) void cvt_bf16(
    const float* __restrict__ xq, const float* __restrict__ xk,
    const float* __restrict__ Wq, const float* __restrict__ Wk,
    const float* __restrict__ Wv, const int* __restrict__ key_mask,
    short* __restrict__ ws)
{
    const int blk = blockIdx.x;
    if (blk >= 11264) {
        float* bias = (float*)(ws + 24117248u);
        const int i0 = threadIdx.x * 4;
#pragma unroll
        for (int p = 0; p < 4; ++p) {
            int idx = p * 1024 + i0;          // 0..4095 = mb*2048 + k
            int4 m = *(const int4*)&key_mask[idx];
            f32x4 o = { m.x ? 0.f : -1e9f, m.y ? 0.f : -1e9f,
                        m.z ? 0.f : -1e9f, m.w ? 0.f : -1e9f };
            *(f32x4*)&bias[idx] = o;
        }
        return;
    }
    int seg, local;
    if (blk < 4096)      { seg = 0; local = blk; }
    else if (blk < 8192) { seg = 1; local = blk - 4096; }
    else                 { seg = 2 + ((blk - 8192) >> 10); local = (blk - 8192) & 1023; }
    const float* src = (seg == 0) ? xq : (seg == 1) ? xk
                     : (seg == 2) ? Wq : (seg == 3) ? Wk : Wv;
    const size_t dstoff = (seg == 0) ? 12582912u : (seg == 1) ? 16777216u
                        : 20971520u + (size_t)(seg - 2) * 1048576u;
    const size_t idx = (size_t)local * 1024 + threadIdx.x * 4;
    float4 v = *(const float4*)&src[idx];
    bf16x4 o = { f2bf(v.x), f2bf(v.y), f2bf(v.z), f2bf(v.w) };
    *(bf16x4*)&ws[dstoff + idx] = o;
}

// ---------------------------------------------------------------------------
// Projection GEMM (bf16): out = x @ W^T + bias.  (R11-verified form)
// z=0: Q -> [bh][t][64]   z=1: K -> [bh][t][64]   z=2: V -> [bh][64][t]
// T2 swizzle both-sides: pre-swizzled global source + swizzled LDS read.
// NOTE: no min-waves launch bound — VGPR 132 is this kernel's natural cost;
// capping it (R8: 128-thread/64x128 tile, R12: min 4 waves/EU) spills acc
// to scratch and regresses 3-10x. 132 VGPR already co-schedules 3 blocks/CU.
// ---------------------------------------------------------------------------
__global__ __launch_bounds__(256) void proj_gemm(
    short* __restrict__ ws, const float* __restrict__ bq,
    const float* __restrict__ bk, const float* __restrict__ bv)
{
    const int z = blockIdx.z;
    const short* A  = ws + ((z == 0) ? 12582912u : 16777216u);
    const short* Bw = ws + 20971520u + (size_t)z * 1048576u;
    const float* bias = (z == 0) ? bq : (z == 1) ? bk : bv;
    short* out = ws + (size_t)z * 4194304u;

    const int m0 = blockIdx.x * 128;
    const int n0 = blockIdx.y * 128;
    const int tid  = threadIdx.x;
    const int lane = tid & 63;
    const int wid  = tid >> 6;
    const int wr = wid >> 1, wc = wid & 1;
    const int l15 = lane & 15, lhi = lane >> 4;

    __shared__ alignas(16) short SM[17408];

    const int srow = wid * 32 + (lane >> 2);
    const int sgrp = (lane & 3) ^ ((lane >> 3) & 3);
    const short* aSrc = A  + (size_t)(m0 + srow) * 1024 + sgrp * 8;
    const short* bSrc = Bw + (size_t)(n0 + srow) * 1024 + sgrp * 8;

#define PSTAGE(T, BUF) do {                                                    \
    _Pragma("unroll")                                                          \
    for (int i_ = 0; i_ < 2; ++i_) {                                           \
        __builtin_amdgcn_global_load_lds(                                      \
            (const __attribute__((address_space(1))) unsigned*)                \
                (aSrc + (T) * 32 + i_ * 16384),                                \
            (__attribute__((address_space(3))) unsigned*)                      \
                &SM[(BUF) * 8192 + (wid * 32 + i_ * 16) * 32], 16, 0, 0);      \
        __builtin_amdgcn_global_load_lds(                                      \
            (const __attribute__((address_space(1))) unsigned*)                \
                (bSrc + (T) * 32 + i_ * 16384),                                \
            (__attribute__((address_space(3))) unsigned*)                      \
                &SM[(BUF) * 8192 + 4096 + (wid * 32 + i_ * 16) * 32], 16, 0, 0);\
    } } while (0)

    f32x4 acc[4][4] = {};

    const int rgrp = (lhi ^ ((l15 >> 1) & 3)) * 8;

    PSTAGE(0, 0);
    for (int t = 0; t < 32; ++t) {
        const int buf = t & 1;
        __syncthreads();
        if (t < 31) PSTAGE(t + 1, buf ^ 1);

        const short* SA = &SM[buf * 8192];
        const short* SB = SA + 4096;
        bf16x8 a[4], b[4];
#pragma unroll
        for (int i = 0; i < 4; ++i)
            a[i] = *(const bf16x8*)&SA[(wr * 64 + i * 16 + l15) * 32 + rgrp];
#pragma unroll
        for (int j = 0; j < 4; ++j)
            b[j] = *(const bf16x8*)&SB[(wc * 64 + j * 16 + l15) * 32 + rgrp];

        if (z == 2) {
#pragma unroll
            for (int i = 0; i < 4; ++i)
#pragma unroll
                for (int j = 0; j < 4; ++j)
                    acc[i][j] = __builtin_amdgcn_mfma_f32_16x16x32_bf16(
                        a[i], b[j], acc[i][j], 0, 0, 0);
        } else {
#pragma unroll
            for (int i = 0; i < 4; ++i)
#pragma unroll
                for (int j = 0; j < 4; ++j)
                    acc[i][j] = __builtin_amdgcn_mfma_f32_16x16x32_bf16(
                        b[j], a[i], acc[i][j], 0, 0, 0);
        }
    }
#undef PSTAGE

    __syncthreads();
    if (z == 2) {
#pragma unroll
        for (int i = 0; i < 4; ++i) {
            int mm = wr * 64 + i * 16 + lhi * 4;
#pragma unroll
            for (int j = 0; j < 4; ++j) {
                int nn = wc * 64 + j * 16 + l15;
                float bval = bias[n0 + nn];
                bf16x4 pk = { f2bf(acc[i][j][0] + bval), f2bf(acc[i][j][1] + bval),
                              f2bf(acc[i][j][2] + bval), f2bf(acc[i][j][3] + bval) };
                *(bf16x4*)&SM[nn * 136 + mm] = pk;
            }
        }
    } else {
#pragma unroll
        for (int i = 0; i < 4; ++i) {
            int mm = wr * 64 + i * 16 + l15;
#pragma unroll
            for (int j = 0; j < 4; ++j) {
                int nnb = wc * 64 + j * 16 + lhi * 4;
                float4 bw = *(const float4*)&bias[n0 + nnb];
                bf16x4 pk = { f2bf(acc[i][j][0] + bw.x), f2bf(acc[i][j][1] + bw.y),
                              f2bf(acc[i][j][2] + bw.z), f2bf(acc[i][j][3] + bw.w) };
                *(bf16x4*)&SM[mm * 136 + nnb] = pk;
            }
        }
    }
    __syncthreads();

    const int bb = m0 >> 11;
    const int mt = m0 & 2047;
#pragma unroll
    for (int p = 0; p < 8; ++p) {
        int id = p * 256 + tid;
        int rr = id >> 4;
        int g  = id & 15;
        bf16x8 v = *(const bf16x8*)&SM[rr * 136 + g * 8];
        if (z == 2) {
            int nn = n0 + rr, h = nn >> 6, d = nn & 63;
            *(bf16x8*)&out[(((size_t)(bb * 16 + h)) * 64 + d) * 2048 + mt + g * 8] = v;
        } else {
            int nn = n0 + g * 8, h = nn >> 6, d = nn & 63;
            *(bf16x8*)&out[(((size_t)(bb * 16 + h)) * 2048 + mt + rr) * 64 + d] = v;
        }
    }
}

// ---------------------------------------------------------------------------
// Flash attention, in-block split-K (unchanged, R11-verified): fixed-offset
// softmax, per-s register-safe processing, lv4 sum accumulator, mask-as-C-init,
// swizzled staging, setprio, pure-add split-K merge.
// ---------------------------------------------------------------------------
__device__ inline float pair_sum(float v) { return v + __shfl_xor(v, 32); }

__global__ __launch_bounds__(512, 4) void attn_fwd(
    const short* __restrict__ Qb, const short* __restrict__ Kb,
    const short* __restrict__ Vtb, const int* __restrict__ key_mask,
    const float* __restrict__ biasArr, float* __restrict__ out)
{
    const int bh = blockIdx.x;        // bh fastest: same-bh blocks -> same XCD
    const int qb = blockIdx.y;
    const int b  = bh >> 4;
    const int h  = bh & 15;
    const int mb = bh & 1;            // (b*H + h) % B, B=2
    const int tid  = threadIdx.x;
    const int lane = tid & 63;
    const int wid  = tid >> 6;        // 0..7
    const int qg   = wid & 3;         // q-group
    const int ks   = wid >> 2;        // k-split half
    const int l31  = lane & 31;
    const int hi   = lane >> 5;

    const size_t base = (size_t)bh * 2048 * 64;
    const int q0 = qb * 128 + qg * 32;
    const int ko = ks * 1024;

    __shared__ alignas(16) char SMEM[65536];
    short* KVbase = (short*)SMEM + ks * 16384;
#define KVS(BUF) (KVbase + (BUF) * 8192)

    const int* km_row = key_mask + mb * 2048;
    const float* bias_row = biasArr + mb * 2048;

    bf16x8 qf[4];
#pragma unroll
    for (int kf = 0; kf < 4; ++kf)
        qf[kf] = *(const bf16x8*)&Qb[base + (size_t)(q0 + l31) * 64 + kf * 16 + hi * 8];

    const int lrow = lane >> 3;
    const int lcol = (lane & 7) ^ (lrow & 7);
    const short* srcK[2];
    const short* srcV[2];
#pragma unroll
    for (int i = 0; i < 2; ++i) {
        int r0 = qg * 16 + i * 8;
        srcK[i] = Kb  + base + (size_t)(ko + r0 + lrow) * 64 + lcol * 8;
        srcV[i] = Vtb + base + (size_t)(r0 + lrow) * 2048 + ko + lcol * 8;
    }

    f32x16 acc[2];
#pragma unroll
    for (int n = 0; n < 2; ++n)
#pragma unroll
        for (int r = 0; r < 16; ++r) acc[n][r] = 0.f;
    float lv4_0 = 0.f, lv4_1 = 0.f, lv4_2 = 0.f, lv4_3 = 0.f;
    const float SC  = 0.18033688f;    // 0.125 * log2(e)
    const float MSC = 8.0f;           // fixed softmax offset (exp2 units)

#define STAGE(T, BUF)                                                          \
    {                                                                          \
        _Pragma("unroll")                                                      \
        for (int i = 0; i < 2; ++i) {                                          \
            int r0 = qg * 16 + i * 8;                                          \
            __builtin_amdgcn_global_load_lds(                                  \
                (const __attribute__((address_space(1))) unsigned int*)        \
                    (srcK[i] + (size_t)(T) * 4096),                            \
                (__attribute__((address_space(3))) unsigned int*)              \
                    &KVS(BUF)[r0 * 64],                                        \
                16, 0, 0);                                                     \
            __builtin_amdgcn_global_load_lds(                                  \
                (const __attribute__((address_space(1))) unsigned int*)        \
                    (srcV[i] + (size_t)(T) * 64),                              \
                (__attribute__((address_space(3))) unsigned int*)              \
                    &KVS(BUF)[4096 + r0 * 64],                                 \
                16, 0, 0);                                                     \
        }                                                                      \
    }

    STAGE(0, 0);

    for (int t = 0; t < 16; ++t) {
        const int buf = t & 1;
        const int k0 = ko + t * 64;
        __syncthreads();
        if (t < 15) STAGE(t + 1, buf ^ 1);

        // S^T = K*Q^T with C initialized to the mask bias (0 / -1e9).
        const f32x4* bp = (const f32x4*)(bias_row + k0);
        f32x16 sacc[2];
#pragma unroll
        for (int s = 0; s < 2; ++s) {
#pragma unroll
            for (int g = 0; g < 4; ++g) {
                f32x4 bv = bp[s * 8 + g * 2 + hi];
#pragma unroll
                for (int c = 0; c < 4; ++c) sacc[s][g * 4 + c] = bv[c];
            }
        }
        __builtin_amdgcn_s_setprio(1);
#pragma unroll
        for (int s = 0; s < 2; ++s) {
#pragma unroll
            for (int kf = 0; kf < 4; ++kf) {
                int row = s * 32 + l31;
                int xg = ((2 * kf + hi) ^ (row & 7)) * 8;
                bf16x8 kfr = *(const bf16x8*)&KVS(buf)[row * 64 + xg];
                sacc[s] = __builtin_amdgcn_mfma_f32_32x32x16_bf16(
                    kfr, qf[kf], sacc[s], 0, 0, 0);
            }
        }
        __builtin_amdgcn_s_setprio(0);

        // fixed-offset softmax, per-s to bound register pressure
        unsigned pk2[2][4][2];
#pragma unroll
        for (int s = 0; s < 2; ++s) {
            float p[16];
#pragma unroll
            for (int r = 0; r < 16; ++r)
                p[r] = __builtin_amdgcn_exp2f(sacc[s][r] * SC - MSC);
            lv4_0 += (p[0] + p[4]) + (p[8]  + p[12]);
            lv4_1 += (p[1] + p[5]) + (p[9]  + p[13]);
            lv4_2 += (p[2] + p[6]) + (p[10] + p[14]);
            lv4_3 += (p[3] + p[7]) + (p[11] + p[15]);
#pragma unroll
            for (int g = 0; g < 4; ++g)
#pragma unroll
                for (int w = 0; w < 2; ++w) {
                    unsigned d;
                    asm("v_cvt_pk_bf16_f32 %0, %1, %2"
                        : "=v"(d)
                        : "v"(p[g * 4 + 2 * w]), "v"(p[g * 4 + 2 * w + 1]));
                    pk2[s][g][w] = d;
                }
        }

        __builtin_amdgcn_s_setprio(1);
#pragma unroll
        for (int s = 0; s < 2; ++s)
#pragma unroll
            for (int kk = 0; kk < 2; ++kk) {
                unsigned w0 = pk2[s][2 * kk][0],     w1 = pk2[s][2 * kk][1];
                unsigned w2 = pk2[s][2 * kk + 1][0], w3 = pk2[s][2 * kk + 1][1];
                asm("v_permlane32_swap_b32 %0, %1" : "+v"(w0), "+v"(w2));
                asm("v_permlane32_swap_b32 %0, %1" : "+v"(w1), "+v"(w3));
                u32x4 fv = { w0, w1, w2, w3 };
                bf16x8 pf = __builtin_bit_cast(bf16x8, fv);
                int kq = s * 2 + kk;
#pragma unroll
                for (int n = 0; n < 2; ++n) {
                    int row = n * 32 + l31;
                    int xg = ((2 * kq + hi) ^ (row & 7)) * 8;
                    bf16x8 vf = *(const bf16x8*)&KVS(buf)[4096 + row * 64 + xg];
                    acc[n] = __builtin_amdgcn_mfma_f32_32x32x16_bf16(
                        vf, pf, acc[n], 0, 0, 0);
                }
            }
        __builtin_amdgcn_s_setprio(0);
    }
#undef STAGE
#undef KVS

    // final row-sum (once) + cross-half
    float lr = pair_sum((lv4_0 + lv4_1) + (lv4_2 + lv4_3));

    // ---- split-K merge (pure add: same fixed offset both halves) ----
    __syncthreads();                       // (A) all KV reads complete
    float* R = (float*)SMEM + qg * 2176;   // per-qg region: O[64][32] | l

    if (ks == 1) {
#pragma unroll
        for (int n = 0; n < 2; ++n)
#pragma unroll
            for (int r = 0; r < 16; ++r) {
                int d = n * 32 + (r & 3) + 8 * (r >> 2) + 4 * hi;
                R[d * 32 + l31] = acc[n][r];
            }
        if (hi == 0) R[2048 + l31] = lr;
    }
    __syncthreads();                       // (B) partner data visible

    if (ks == 0) {
        float l1 = R[2048 + l31];
        float o1[2][16];
#pragma unroll
        for (int n = 0; n < 2; ++n)
#pragma unroll
            for (int r = 0; r < 16; ++r) {
                int d = n * 32 + (r & 3) + 8 * (r >> 2) + 4 * hi;
                o1[n][r] = R[d * 32 + l31];
            }
        float qn = (float)km_row[q0 + l31] / (lr + l1);

#pragma unroll
        for (int n = 0; n < 2; ++n)
#pragma unroll
            for (int r = 0; r < 16; ++r) {
                int d = n * 32 + (r & 3) + 8 * (r >> 2) + 4 * hi;
                R[l31 * 68 + d] = (acc[n][r] + o1[n][r]) * qn;
            }
        const int l15 = lane & 15, lq = lane >> 4;
#pragma unroll
        for (int rep = 0; rep < 8; ++rep) {
            int qr = rep * 4 + lq;
            f32x4 v = *(const f32x4*)&R[qr * 68 + l15 * 4];
            *(f32x4*)&out[((size_t)b * 2048 + q0 + qr) * 1024 + h * 64 + l15 * 4] = v;
        }
    }
}

extern "C" void kernel_launch(void* const* d_in, const int* in_sizes, int n_in,
                              void* d_out, int out_size, void* d_ws, size_t ws_size,
                              hipStream_t stream) {
    const float* queries = (const float*)d_in[0];
    const float* keys    = (const float*)d_in[1];
    const int*   key_mask= (const int*)d_in[2];
    const float* Wq = (const float*)d_in[3];
    const float* bq = (const float*)d_in[4];
    const float* Wk = (const float*)d_in[5];
    const float* bk = (const float*)d_in[6];
    const float* Wv = (const float*)d_in[7];
    const float* bv = (const float*)d_in[8];
    float* out = (float*)d_out;

    short* ws = (short*)d_ws;
    const float* biasArr = (const float*)(ws + 24117248u);

    cvt_bf16<<<11265, 256, 0, stream>>>(queries, keys, Wq, Wk, Wv, key_mask, ws);

    proj_gemm<<<dim3(32, 8, 3), 256, 0, stream>>>(ws, bq, bk, bv);

    attn_fwd<<<dim3(32, 16), 512, 0, stream>>>(
        ws, ws + 4194304, ws + 2 * 4194304, key_mask, biasArr, out);
}

// Round 14
// 110.832 us; speedup vs baseline: 2.6281x; 1.0210x over previous
//
#include <hip/hip_runtime.h>
#include <hip/hip_bf16.h>

typedef __attribute__((ext_vector_type(8))) short bf16x8;
typedef __attribute__((ext_vector_type(4))) short bf16x4;
typedef __attribute__((ext_vector_type(4))) float f32x4;
typedef __attribute__((ext_vector_type(16))) float f32x16;
typedef __attribute__((ext_vector_type(4))) unsigned u32x4;

__device__ inline short f2bf(float f) {
    unsigned u = __builtin_bit_cast(unsigned, f);
    u += 0x7FFF + ((u >> 16) & 1);   // round-to-nearest-even
    return (short)(u >> 16);
}

#define SOFT_SC 0.18033688f   // (1/sqrt(64)) * log2(e) — folded into Wq/bq
#define SOFT_MSC 8.0f         // fixed softmax offset (exp2 units) — folded into mask bias

// ws layout (units: shorts/bf16):
//   0        : Q(pre-scaled by SOFT_SC) [32][2048][64]
//   4194304  : K   [32][2048][64]
//   8388608  : V^T [32][64][2048]
//   12582912 : xq_bf16 [4096][1024]
//   16777216 : xk_bf16 [4096][1024]
//   20971520 : Wq_bf16*SC [1024][1024]; +1M: Wk; +2M: Wv
//   24117248 : mask bias f32[2][2048] (= -MSC or -1e9), 16KB

// ---------------------------------------------------------------------------
// f32 -> bf16 convert (memory-bound) + mask-bias build (block 11264).
// Wq scaled by SOFT_SC; mask bias carries -SOFT_MSC for unmasked keys.
// ---------------------------------------------------------------------------
__global__ __launch_bounds__(256) void cvt_bf16(
    const float* __restrict__ xq, const float* __restrict__ xk,
    const float* __restrict__ Wq, const float* __restrict__ Wk,
    const float* __restrict__ Wv, const int* __restrict__ key_mask,
    short* __restrict__ ws)
{
    const int blk = blockIdx.x;
    if (blk >= 11264) {
        float* bias = (float*)(ws + 24117248u);
        const int i0 = threadIdx.x * 4;
#pragma unroll
        for (int p = 0; p < 4; ++p) {
            int idx = p * 1024 + i0;          // 0..4095 = mb*2048 + k
            int4 m = *(const int4*)&key_mask[idx];
            f32x4 o = { m.x ? -SOFT_MSC : -1e9f, m.y ? -SOFT_MSC : -1e9f,
                        m.z ? -SOFT_MSC : -1e9f, m.w ? -SOFT_MSC : -1e9f };
            *(f32x4*)&bias[idx] = o;
        }
        return;
    }
    int seg, local;
    if (blk < 4096)      { seg = 0; local = blk; }
    else if (blk < 8192) { seg = 1; local = blk - 4096; }
    else                 { seg = 2 + ((blk - 8192) >> 10); local = (blk - 8192) & 1023; }
    const float* src = (seg == 0) ? xq : (seg == 1) ? xk
                     : (seg == 2) ? Wq : (seg == 3) ? Wk : Wv;
    const size_t dstoff = (seg == 0) ? 12582912u : (seg == 1) ? 16777216u
                        : 20971520u + (size_t)(seg - 2) * 1048576u;
    const float sc = (seg == 2) ? SOFT_SC : 1.0f;   // fold softmax scale into Wq
    const size_t idx = (size_t)local * 1024 + threadIdx.x * 4;
    float4 v = *(const float4*)&src[idx];
    bf16x4 o = { f2bf(v.x * sc), f2bf(v.y * sc), f2bf(v.z * sc), f2bf(v.w * sc) };
    *(bf16x4*)&ws[dstoff + idx] = o;
}

// ---------------------------------------------------------------------------
// Projection GEMM (bf16): out = x @ W^T + bias.  (R11/R13-verified form)
// z=0: Q -> [bh][t][64] (pre-scaled)  z=1: K -> [bh][t][64]  z=2: V -> [bh][64][t]
// T2 swizzle both-sides: pre-swizzled global source + swizzled LDS read.
// NOTE: no min-waves launch bound — VGPR 132 is this kernel's natural cost;
// capping it (R8/R12) spills acc to scratch and regresses 3-10x.
// ---------------------------------------------------------------------------
__global__ __launch_bounds__(256) void proj_gemm(
    short* __restrict__ ws, const float* __restrict__ bq,
    const float* __restrict__ bk, const float* __restrict__ bv)
{
    const int z = blockIdx.z;
    const short* A  = ws + ((z == 0) ? 12582912u : 16777216u);
    const short* Bw = ws + 20971520u + (size_t)z * 1048576u;
    const float* bias = (z == 0) ? bq : (z == 1) ? bk : bv;
    const float bsc = (z == 0) ? SOFT_SC : 1.0f;   // bq folded scale
    short* out = ws + (size_t)z * 4194304u;

    const int m0 = blockIdx.x * 128;
    const int n0 = blockIdx.y * 128;
    const int tid  = threadIdx.x;
    const int lane = tid & 63;
    const int wid  = tid >> 6;
    const int wr = wid >> 1, wc = wid & 1;
    const int l15 = lane & 15, lhi = lane >> 4;

    __shared__ alignas(16) short SM[17408];

    const int srow = wid * 32 + (lane >> 2);
    const int sgrp = (lane & 3) ^ ((lane >> 3) & 3);
    const short* aSrc = A  + (size_t)(m0 + srow) * 1024 + sgrp * 8;
    const short* bSrc = Bw + (size_t)(n0 + srow) * 1024 + sgrp * 8;

#define PSTAGE(T, BUF) do {                                                    \
    _Pragma("unroll")                                                          \
    for (int i_ = 0; i_ < 2; ++i_) {                                           \
        __builtin_amdgcn_global_load_lds(                                      \
            (const __attribute__((address_space(1))) unsigned*)                \
                (aSrc + (T) * 32 + i_ * 16384),                                \
            (__attribute__((address_space(3))) unsigned*)                      \
                &SM[(BUF) * 8192 + (wid * 32 + i_ * 16) * 32], 16, 0, 0);      \
        __builtin_amdgcn_global_load_lds(                                      \
            (const __attribute__((address_space(1))) unsigned*)                \
                (bSrc + (T) * 32 + i_ * 16384),                                \
            (__attribute__((address_space(3))) unsigned*)                      \
                &SM[(BUF) * 8192 + 4096 + (wid * 32 + i_ * 16) * 32], 16, 0, 0);\
    } } while (0)

    f32x4 acc[4][4] = {};

    const int rgrp = (lhi ^ ((l15 >> 1) & 3)) * 8;

    PSTAGE(0, 0);
    for (int t = 0; t < 32; ++t) {
        const int buf = t & 1;
        __syncthreads();
        if (t < 31) PSTAGE(t + 1, buf ^ 1);

        const short* SA = &SM[buf * 8192];
        const short* SB = SA + 4096;
        bf16x8 a[4], b[4];
#pragma unroll
        for (int i = 0; i < 4; ++i)
            a[i] = *(const bf16x8*)&SA[(wr * 64 + i * 16 + l15) * 32 + rgrp];
#pragma unroll
        for (int j = 0; j < 4; ++j)
            b[j] = *(const bf16x8*)&SB[(wc * 64 + j * 16 + l15) * 32 + rgrp];

        if (z == 2) {
#pragma unroll
            for (int i = 0; i < 4; ++i)
#pragma unroll
                for (int j = 0; j < 4; ++j)
                    acc[i][j] = __builtin_amdgcn_mfma_f32_16x16x32_bf16(
                        a[i], b[j], acc[i][j], 0, 0, 0);
        } else {
#pragma unroll
            for (int i = 0; i < 4; ++i)
#pragma unroll
                for (int j = 0; j < 4; ++j)
                    acc[i][j] = __builtin_amdgcn_mfma_f32_16x16x32_bf16(
                        b[j], a[i], acc[i][j], 0, 0, 0);
        }
    }
#undef PSTAGE

    __syncthreads();
    if (z == 2) {
#pragma unroll
        for (int i = 0; i < 4; ++i) {
            int mm = wr * 64 + i * 16 + lhi * 4;
#pragma unroll
            for (int j = 0; j < 4; ++j) {
                int nn = wc * 64 + j * 16 + l15;
                float bval = bias[n0 + nn];
                bf16x4 pk = { f2bf(acc[i][j][0] + bval), f2bf(acc[i][j][1] + bval),
                              f2bf(acc[i][j][2] + bval), f2bf(acc[i][j][3] + bval) };
                *(bf16x4*)&SM[nn * 136 + mm] = pk;
            }
        }
    } else {
#pragma unroll
        for (int i = 0; i < 4; ++i) {
            int mm = wr * 64 + i * 16 + l15;
#pragma unroll
            for (int j = 0; j < 4; ++j) {
                int nnb = wc * 64 + j * 16 + lhi * 4;
                float4 bw = *(const float4*)&bias[n0 + nnb];
                bf16x4 pk = { f2bf(acc[i][j][0] + bw.x * bsc),
                              f2bf(acc[i][j][1] + bw.y * bsc),
                              f2bf(acc[i][j][2] + bw.z * bsc),
                              f2bf(acc[i][j][3] + bw.w * bsc) };
                *(bf16x4*)&SM[mm * 136 + nnb] = pk;
            }
        }
    }
    __syncthreads();

    const int bb = m0 >> 11;
    const int mt = m0 & 2047;
#pragma unroll
    for (int p = 0; p < 8; ++p) {
        int id = p * 256 + tid;
        int rr = id >> 4;
        int g  = id & 15;
        bf16x8 v = *(const bf16x8*)&SM[rr * 136 + g * 8];
        if (z == 2) {
            int nn = n0 + rr, h = nn >> 6, d = nn & 63;
            *(bf16x8*)&out[(((size_t)(bb * 16 + h)) * 64 + d) * 2048 + mt + g * 8] = v;
        } else {
            int nn = n0 + g * 8, h = nn >> 6, d = nn & 63;
            *(bf16x8*)&out[(((size_t)(bb * 16 + h)) * 2048 + mt + rr) * 64 + d] = v;
        }
    }
}

// ---------------------------------------------------------------------------
// Flash attention, in-block split-K. R14: Q pre-scaled + offset-in-bias ->
// p = exp2(sacc) directly (32 fewer v_fma per tile-step per wave on the
// serial MFMA->softmax->MFMA chain). Else identical to R11/R13-verified.
// ---------------------------------------------------------------------------
__device__ inline float pair_sum(float v) { return v + __shfl_xor(v, 32); }

__global__ __launch_bounds__(512, 4) void attn_fwd(
    const short* __restrict__ Qb, const short* __restrict__ Kb,
    const short* __restrict__ Vtb, const int* __restrict__ key_mask,
    const float* __restrict__ biasArr, float* __restrict__ out)
{
    const int bh = blockIdx.x;        // bh fastest: same-bh blocks -> same XCD
    const int qb = blockIdx.y;
    const int b  = bh >> 4;
    const int h  = bh & 15;
    const int mb = bh & 1;            // (b*H + h) % B, B=2
    const int tid  = threadIdx.x;
    const int lane = tid & 63;
    const int wid  = tid >> 6;        // 0..7
    const int qg   = wid & 3;         // q-group
    const int ks   = wid >> 2;        // k-split half
    const int l31  = lane & 31;
    const int hi   = lane >> 5;

    const size_t base = (size_t)bh * 2048 * 64;
    const int q0 = qb * 128 + qg * 32;
    const int ko = ks * 1024;

    __shared__ alignas(16) char SMEM[65536];
    short* KVbase = (short*)SMEM + ks * 16384;
#define KVS(BUF) (KVbase + (BUF) * 8192)

    const int* km_row = key_mask + mb * 2048;
    const float* bias_row = biasArr + mb * 2048;

    bf16x8 qf[4];
#pragma unroll
    for (int kf = 0; kf < 4; ++kf)
        qf[kf] = *(const bf16x8*)&Qb[base + (size_t)(q0 + l31) * 64 + kf * 16 + hi * 8];

    const int lrow = lane >> 3;
    const int lcol = (lane & 7) ^ (lrow & 7);
    const short* srcK[2];
    const short* srcV[2];
#pragma unroll
    for (int i = 0; i < 2; ++i) {
        int r0 = qg * 16 + i * 8;
        srcK[i] = Kb  + base + (size_t)(ko + r0 + lrow) * 64 + lcol * 8;
        srcV[i] = Vtb + base + (size_t)(r0 + lrow) * 2048 + ko + lcol * 8;
    }

    f32x16 acc[2];
#pragma unroll
    for (int n = 0; n < 2; ++n)
#pragma unroll
        for (int r = 0; r < 16; ++r) acc[n][r] = 0.f;
    float lv4_0 = 0.f, lv4_1 = 0.f, lv4_2 = 0.f, lv4_3 = 0.f;

#define STAGE(T, BUF)                                                          \
    {                                                                          \
        _Pragma("unroll")                                                      \
        for (int i = 0; i < 2; ++i) {                                          \
            int r0 = qg * 16 + i * 8;                                          \
            __builtin_amdgcn_global_load_lds(                                  \
                (const __attribute__((address_space(1))) unsigned int*)        \
                    (srcK[i] + (size_t)(T) * 4096),                            \
                (__attribute__((address_space(3))) unsigned int*)              \
                    &KVS(BUF)[r0 * 64],                                        \
                16, 0, 0);                                                     \
            __builtin_amdgcn_global_load_lds(                                  \
                (const __attribute__((address_space(1))) unsigned int*)        \
                    (srcV[i] + (size_t)(T) * 64),                              \
                (__attribute__((address_space(3))) unsigned int*)              \
                    &KVS(BUF)[4096 + r0 * 64],                                 \
                16, 0, 0);                                                     \
        }                                                                      \
    }

    STAGE(0, 0);

    for (int t = 0; t < 16; ++t) {
        const int buf = t & 1;
        const int k0 = ko + t * 64;
        __syncthreads();
        if (t < 15) STAGE(t + 1, buf ^ 1);

        // S^T = K*(Q*SC)^T with C initialized to (-MSC / -1e9) mask bias.
        const f32x4* bp = (const f32x4*)(bias_row + k0);
        f32x16 sacc[2];
#pragma unroll
        for (int s = 0; s < 2; ++s) {
#pragma unroll
            for (int g = 0; g < 4; ++g) {
                f32x4 bv = bp[s * 8 + g * 2 + hi];
#pragma unroll
                for (int c = 0; c < 4; ++c) sacc[s][g * 4 + c] = bv[c];
            }
        }
        __builtin_amdgcn_s_setprio(1);
#pragma unroll
        for (int s = 0; s < 2; ++s) {
#pragma unroll
            for (int kf = 0; kf < 4; ++kf) {
                int row = s * 32 + l31;
                int xg = ((2 * kf + hi) ^ (row & 7)) * 8;
                bf16x8 kfr = *(const bf16x8*)&KVS(buf)[row * 64 + xg];
                sacc[s] = __builtin_amdgcn_mfma_f32_32x32x16_bf16(
                    kfr, qf[kf], sacc[s], 0, 0, 0);
            }
        }
        __builtin_amdgcn_s_setprio(0);

        // fixed-offset softmax (scale+offset pre-folded): p = exp2(sacc)
        unsigned pk2[2][4][2];
#pragma unroll
        for (int s = 0; s < 2; ++s) {
            float p[16];
#pragma unroll
            for (int r = 0; r < 16; ++r)
                p[r] = __builtin_amdgcn_exp2f(sacc[s][r]);
            lv4_0 += (p[0] + p[4]) + (p[8]  + p[12]);
            lv4_1 += (p[1] + p[5]) + (p[9]  + p[13]);
            lv4_2 += (p[2] + p[6]) + (p[10] + p[14]);
            lv4_3 += (p[3] + p[7]) + (p[11] + p[15]);
#pragma unroll
            for (int g = 0; g < 4; ++g)
#pragma unroll
                for (int w = 0; w < 2; ++w) {
                    unsigned d;
                    asm("v_cvt_pk_bf16_f32 %0, %1, %2"
                        : "=v"(d)
                        : "v"(p[g * 4 + 2 * w]), "v"(p[g * 4 + 2 * w + 1]));
                    pk2[s][g][w] = d;
                }
        }

        __builtin_amdgcn_s_setprio(1);
#pragma unroll
        for (int s = 0; s < 2; ++s)
#pragma unroll
            for (int kk = 0; kk < 2; ++kk) {
                unsigned w0 = pk2[s][2 * kk][0],     w1 = pk2[s][2 * kk][1];
                unsigned w2 = pk2[s][2 * kk + 1][0], w3 = pk2[s][2 * kk + 1][1];
                asm("v_permlane32_swap_b32 %0, %1" : "+v"(w0), "+v"(w2));
                asm("v_permlane32_swap_b32 %0, %1" : "+v"(w1), "+v"(w3));
                u32x4 fv = { w0, w1, w2, w3 };
                bf16x8 pf = __builtin_bit_cast(bf16x8, fv);
                int kq = s * 2 + kk;
#pragma unroll
                for (int n = 0; n < 2; ++n) {
                    int row = n * 32 + l31;
                    int xg = ((2 * kq + hi) ^ (row & 7)) * 8;
                    bf16x8 vf = *(const bf16x8*)&KVS(buf)[4096 + row * 64 + xg];
                    acc[n] = __builtin_amdgcn_mfma_f32_32x32x16_bf16(
                        vf, pf, acc[n], 0, 0, 0);
                }
            }
        __builtin_amdgcn_s_setprio(0);
    }
#undef STAGE
#undef KVS

    // final row-sum (once) + cross-half
    float lr = pair_sum((lv4_0 + lv4_1) + (lv4_2 + lv4_3));

    // ---- split-K merge (pure add: same fixed offset both halves) ----
    __syncthreads();                       // (A) all KV reads complete
    float* R = (float*)SMEM + qg * 2176;   // per-qg region: O[64][32] | l

    if (ks == 1) {
#pragma unroll
        for (int n = 0; n < 2; ++n)
#pragma unroll
            for (int r = 0; r < 16; ++r) {
                int d = n * 32 + (r & 3) + 8 * (r >> 2) + 4 * hi;
                R[d * 32 + l31] = acc[n][r];
            }
        if (hi == 0) R[2048 + l31] = lr;
    }
    __syncthreads();                       // (B) partner data visible

    if (ks == 0) {
        float l1 = R[2048 + l31];
        float o1[2][16];
#pragma unroll
        for (int n = 0; n < 2; ++n)
#pragma unroll
            for (int r = 0; r < 16; ++r) {
                int d = n * 32 + (r & 3) + 8 * (r >> 2) + 4 * hi;
                o1[n][r] = R[d * 32 + l31];
            }
        float qn = (float)km_row[q0 + l31] / (lr + l1);

#pragma unroll
        for (int n = 0; n < 2; ++n)
#pragma unroll
            for (int r = 0; r < 16; ++r) {
                int d = n * 32 + (r & 3) + 8 * (r >> 2) + 4 * hi;
                R[l31 * 68 + d] = (acc[n][r] + o1[n][r]) * qn;
            }
        const int l15 = lane & 15, lq = lane >> 4;
#pragma unroll
        for (int rep = 0; rep < 8; ++rep) {
            int qr = rep * 4 + lq;
            f32x4 v = *(const f32x4*)&R[qr * 68 + l15 * 4];
            *(f32x4*)&out[((size_t)b * 2048 + q0 + qr) * 1024 + h * 64 + l15 * 4] = v;
        }
    }
}

extern "C" void kernel_launch(void* const* d_in, const int* in_sizes, int n_in,
                              void* d_out, int out_size, void* d_ws, size_t ws_size,
                              hipStream_t stream) {
    const float* queries = (const float*)d_in[0];
    const float* keys    = (const float*)d_in[1];
    const int*   key_mask= (const int*)d_in[2];
    const float* Wq = (const float*)d_in[3];
    const float* bq = (const float*)d_in[4];
    const float* Wk = (const float*)d_in[5];
    const float* bk = (const float*)d_in[6];
    const float* Wv = (const float*)d_in[7];
    const float* bv = (const float*)d_in[8];
    float* out = (float*)d_out;

    short* ws = (short*)d_ws;
    const float* biasArr = (const float*)(ws + 24117248u);

    cvt_bf16<<<11265, 256, 0, stream>>>(queries, keys, Wq, Wk, Wv, key_mask, ws);

    proj_gemm<<<dim3(32, 8, 3), 256, 0, stream>>>(ws, bq, bk, bv);

    attn_fwd<<<dim3(32, 16), 512, 0, stream>>>(
        ws, ws + 4194304, ws + 2 * 4194304, key_mask, biasArr, out);
}